// Round 8
// baseline (637.122 us; speedup 1.0000x reference)
//
#include <hip/hip_runtime.h>

#define N_NODES 100000
#define N_EDGES 1600000
#define BN_EPS 1e-5f
#define NB_SCAN 98   // ceil(100000/1024)

typedef unsigned long long ull;

// broadcast lane k's value (readlane). Wave-uniform control flow ONLY.
__device__ __forceinline__ float bcast(float v, int k) {
    return __uint_as_float(__builtin_amdgcn_readlane(__float_as_uint(v), k));
}
__device__ __forceinline__ float bf16lo(unsigned int w) {
    return __uint_as_float(w << 16);
}
__device__ __forceinline__ float bf16hi(unsigned int w) {
    return __uint_as_float(w & 0xFFFF0000u);
}
__device__ __forceinline__ unsigned short f2bf(float x) {   // round-nearest-even
    unsigned int u = __float_as_uint(x);
    return (unsigned short)((u + 0x7FFF + ((u >> 16) & 1)) >> 16);
}

// ===========================================================================
// CSR build: histogram -> 3-kernel exclusive scan -> fill (single pass;
// R7's 4-pass segmented fill regressed: per-XCD L2s can't merge a shared
// random write window, and each pass re-reads all of dst).
// ===========================================================================
__global__ __launch_bounds__(256) void histogram_kernel(
    const int* __restrict__ dst, int* __restrict__ deg)
{
    int e = blockIdx.x * 256 + threadIdx.x;
    if (e < N_EDGES) atomicAdd(&deg[dst[e]], 1);
}

__global__ __launch_bounds__(1024) void scan1_kernel(
    const int* __restrict__ deg, int* __restrict__ offs, int* __restrict__ bsum)
{
    __shared__ int tmp[1024];
    int gid = blockIdx.x * 1024 + threadIdx.x;
    int v = (gid < N_NODES) ? deg[gid] : 0;
    tmp[threadIdx.x] = v;
    __syncthreads();
    for (int off = 1; off < 1024; off <<= 1) {
        int t = (threadIdx.x >= off) ? tmp[threadIdx.x - off] : 0;
        __syncthreads();
        tmp[threadIdx.x] += t;
        __syncthreads();
    }
    if (gid < N_NODES) offs[gid] = tmp[threadIdx.x] - v;
    if (threadIdx.x == 1023) bsum[blockIdx.x] = tmp[1023];
}

__global__ void scan2_kernel(int* __restrict__ bsum)
{
    __shared__ int tmp[128];
    int v = (threadIdx.x < NB_SCAN) ? bsum[threadIdx.x] : 0;
    tmp[threadIdx.x] = v;
    __syncthreads();
    for (int off = 1; off < 128; off <<= 1) {
        int t = (threadIdx.x >= off) ? tmp[threadIdx.x - off] : 0;
        __syncthreads();
        tmp[threadIdx.x] += t;
        __syncthreads();
    }
    if (threadIdx.x < NB_SCAN) bsum[threadIdx.x] = tmp[threadIdx.x] - v;
}

__global__ __launch_bounds__(1024) void scan3_kernel(
    int* __restrict__ offs, const int* __restrict__ bsum, int* __restrict__ cursor)
{
    int gid = blockIdx.x * 1024 + threadIdx.x;
    if (gid < N_NODES) {
        int v = offs[gid] + bsum[blockIdx.x];
        offs[gid] = v;
        cursor[gid] = v;
    }
    if (gid == 0) offs[N_NODES] = N_EDGES;
}

__global__ __launch_bounds__(256) void fill_kernel(
    const int* __restrict__ src, const int* __restrict__ dst,
    int* __restrict__ cursor, int* __restrict__ nbr)
{
    int e = blockIdx.x * 256 + threadIdx.x;
    if (e < N_EDGES) {
        int p = atomicAdd(&cursor[dst[e]], 1);
        nbr[p] = src[e];
    }
}

// ===========================================================================
// dense1_lin: u(bf16) = x @ W1l^T ; hv(f32) = x @ W1r^T + b1.
// ===========================================================================
__global__ __launch_bounds__(256) void dense1_lin_kernel(
    const float* __restrict__ x, const float* __restrict__ W1l,
    const float* __restrict__ W1r, const float* __restrict__ b1,
    unsigned short* __restrict__ u, float* __restrict__ hv)
{
    __shared__ float wlT[64 * 65];
    __shared__ float wrT[64 * 65];
    for (int idx = threadIdx.x; idx < 4096; idx += 256) {
        int f = idx >> 6, k = idx & 63;
        wlT[k * 65 + f] = W1l[idx];
        wrT[k * 65 + f] = W1r[idx];
    }
    __syncthreads();

    int f  = threadIdx.x & 63;
    int wv = threadIdx.x >> 6;
    float wl[64], wr[64];
#pragma unroll
    for (int k = 0; k < 64; ++k) {
        wl[k] = wlT[k * 65 + f];
        wr[k] = wrT[k * 65 + f];
    }
    float bias = b1[f];
    int node0 = blockIdx.x * 64;

    for (int nn = 0; nn < 16; ++nn) {
        int node = node0 + nn * 4 + wv;          // wave-uniform
        if (node < N_NODES) {
            float xv = x[(size_t)node * 64 + f];
            float ua = 0.f, va = bias;
#pragma unroll
            for (int k = 0; k < 64; ++k) {
                float xb = bcast(xv, k);
                ua += xb * wl[k];
                va += xb * wr[k];
            }
            u[(size_t)node * 64 + f]  = f2bf(ua);
            hv[(size_t)node * 64 + f] = va;
        }
    }
}

// ===========================================================================
// gather1_bn v4: h = mean(u[nbr]) + v (in place over hv) + BN partial sums.
// Quarter-wave edges: 16 lanes x dwordx2 cover one 128B row -> 4 edges per
// load instruction, 32 edges in flight per node (one dependency round for
// deg<=32). offs preloaded once per wave; neighbor ids for node nn+1
// prefetched during node nn (double buffer) -> nbr latency off the chain.
// ===========================================================================
__global__ __launch_bounds__(256) void gather1_bn_kernel(
    const ull* __restrict__ u64p, const int* __restrict__ offs,
    const int* __restrict__ nbr, float* __restrict__ hv,
    float* __restrict__ sums, float* __restrict__ sumsq)
{
    int lane = threadIdx.x & 63;
    int q    = lane >> 4;          // quarter 0..3
    int l    = lane & 15;          // lane in quarter: feats 4l..4l+3
    int wv   = threadIdx.x >> 6;
    int node0 = blockIdx.x * 64;

    // preload beg/end for this wave's 16 nodes (lanes 0..31 carry data)
    int oidx = node0 + wv + (lane >> 1) * 4 + (lane & 1);
    int ov = offs[min(oidx, N_NODES)];

    // prefetch ids for node nn=0
    int beg_c = __shfl(ov, 0), end_c = __shfl(ov, 1);
    int safe0 = min(max(end_c - 1, beg_c), N_EDGES - 1);
    int id_pref = nbr[min(beg_c + lane, safe0)];

    float s1a0=0,s1a1=0,s1a2=0,s1a3=0;    // BN partials (lane<16 only valid)
    float s2a0=0,s2a1=0,s2a2=0,s2a3=0;

    for (int nn = 0; nn < 16; ++nn) {
        int beg = beg_c, end = end_c;
        int id  = id_pref;
        if (nn < 15) {                     // advance prefetch for next node
            beg_c = __shfl(ov, 2 * nn + 2);
            end_c = __shfl(ov, 2 * nn + 3);
            int safe = min(max(end_c - 1, beg_c), N_EDGES - 1);
            id_pref = nbr[min(beg_c + lane, safe)];
        }
        int node = node0 + nn * 4 + wv;
        if (node < N_NODES) {              // wave-uniform
            int deg = end - beg;
            float a0=0,a1=0,a2=0,a3=0, b0=0,b1=0,b2=0,b3=0;
            for (int c = 0; c < deg; c += 64) {
                if (c > 0) {               // rare: deg > 64
                    int safe = min(max(end - 1, beg), N_EDGES - 1);
                    id = nbr[min(beg + c + lane, safe)];
                }
                int cnt = min(deg - c, 64);
                for (int r = 0; r < cnt; r += 32) {    // wave-uniform trips
#pragma unroll
                    for (int i = 0; i < 8; ++i) {
                        int e   = r + i * 4 + q;               // < 64
                        int ide = __shfl(id, min(e, cnt - 1));
                        ull w   = u64p[(size_t)ide * 16 + l];
                        bool val = (e < cnt);
                        unsigned int wlo = (unsigned int)w;
                        unsigned int whi = (unsigned int)(w >> 32);
                        float f0 = val ? bf16lo(wlo) : 0.f;
                        float f1 = val ? bf16hi(wlo) : 0.f;
                        float f2 = val ? bf16lo(whi) : 0.f;
                        float f3 = val ? bf16hi(whi) : 0.f;
                        if (i & 1) { b0 += f0; b1 += f1; b2 += f2; b3 += f3; }
                        else       { a0 += f0; a1 += f1; a2 += f2; a3 += f3; }
                    }
                }
            }
            a0 += b0; a1 += b1; a2 += b2; a3 += b3;
            // combine quarters (all lanes active)
            a0 += __shfl_xor(a0, 16); a0 += __shfl_xor(a0, 32);
            a1 += __shfl_xor(a1, 16); a1 += __shfl_xor(a1, 32);
            a2 += __shfl_xor(a2, 16); a2 += __shfl_xor(a2, 32);
            a3 += __shfl_xor(a3, 16); a3 += __shfl_xor(a3, 32);
            if (lane < 16) {
                float inv = 1.0f / (float)max(deg, 1);
                float4 v = ((const float4*)hv)[(size_t)node * 16 + l];
                float h0 = a0 * inv + v.x;
                float h1 = a1 * inv + v.y;
                float h2 = a2 * inv + v.z;
                float h3 = a3 * inv + v.w;
                ((float4*)hv)[(size_t)node * 16 + l] = make_float4(h0,h1,h2,h3);
                s1a0 += h0; s1a1 += h1; s1a2 += h2; s1a3 += h3;
                s2a0 += h0*h0; s2a1 += h1*h1; s2a2 += h2*h2; s2a3 += h3*h3;
            }
        }
    }

    __shared__ float4 redA[64];
    __shared__ float4 redB[64];
    if (lane < 16) {
        redA[wv * 16 + l] = make_float4(s1a0, s1a1, s1a2, s1a3);
        redB[wv * 16 + l] = make_float4(s2a0, s2a1, s2a2, s2a3);
    }
    __syncthreads();
    if (threadIdx.x < 16) {
        int t = threadIdx.x;
        float4 A = redA[t]; float4 B = redB[t];
        for (int w = 1; w < 4; ++w) {
            float4 a = redA[w * 16 + t]; A.x+=a.x; A.y+=a.y; A.z+=a.z; A.w+=a.w;
            float4 b = redB[w * 16 + t]; B.x+=b.x; B.y+=b.y; B.z+=b.z; B.w+=b.w;
        }
        atomicAdd(&sums[4*t+0], A.x); atomicAdd(&sums[4*t+1], A.y);
        atomicAdd(&sums[4*t+2], A.z); atomicAdd(&sums[4*t+3], A.w);
        atomicAdd(&sumsq[4*t+0], B.x); atomicAdd(&sumsq[4*t+1], B.y);
        atomicAdd(&sumsq[4*t+2], B.z); atomicAdd(&sumsq[4*t+3], B.w);
    }
}

// ===========================================================================
// BN finalize
// ===========================================================================
__global__ void bn_finalize_kernel(
    const float* __restrict__ sums, const float* __restrict__ sumsq,
    const float* __restrict__ gamma, const float* __restrict__ beta,
    float* __restrict__ scale, float* __restrict__ shift)
{
    int f = threadIdx.x;
    if (f < 64) {
        float inv_n = 1.0f / (float)N_NODES;
        float mu  = sums[f] * inv_n;
        float var = sumsq[f] * inv_n - mu * mu;
        float rs  = rsqrtf(var + BN_EPS);
        float sc  = gamma[f] * rs;
        scale[f] = sc;
        shift[f] = beta[f] - mu * sc;
    }
}

// ===========================================================================
// dense2_bn: BN+ReLU fused; tmp(bf16, 40/row, 80B) = hn @ W2l^T;
// out = hn @ W2r^T + b2. Uniform readlane flow; stores predicated.
// ===========================================================================
__global__ __launch_bounds__(256) void dense2_bn_kernel(
    const float* __restrict__ h, const float* __restrict__ scale,
    const float* __restrict__ shift, const float* __restrict__ W2l,
    const float* __restrict__ W2r, const float* __restrict__ b2,
    unsigned short* __restrict__ tmp, float* __restrict__ out)
{
    __shared__ float wlT[64 * 65];
    __shared__ float wrT[64 * 65];
    for (int idx = threadIdx.x; idx < 2560; idx += 256) {
        int f = idx >> 6, k = idx & 63;      // f < 40
        wlT[k * 65 + f] = W2l[idx];
        wrT[k * 65 + f] = W2r[idx];
    }
    __syncthreads();

    int f  = threadIdx.x & 63;
    int wv = threadIdx.x >> 6;
    int fc = (f < 40) ? f : 39;
    float wl[64], wr[64];
#pragma unroll
    for (int k = 0; k < 64; ++k) {
        wl[k] = wlT[k * 65 + fc];
        wr[k] = wrT[k * 65 + fc];
    }
    float bias = b2[fc];
    float sc = scale[f], sh = shift[f];
    int node0 = blockIdx.x * 64;

    for (int nn = 0; nn < 16; ++nn) {
        int node = node0 + nn * 4 + wv;          // wave-uniform
        if (node < N_NODES) {
            float hvv = h[(size_t)node * 64 + f];
            float hn  = fmaxf(hvv * sc + sh, 0.f);   // BN + ReLU fused
            float ta = 0.f, ra = bias;
#pragma unroll
            for (int k = 0; k < 64; ++k) {
                float hb = bcast(hn, k);
                ta += hb * wl[k];
                ra += hb * wr[k];
            }
            if (f < 40) {
                tmp[(size_t)node * 40 + f] = f2bf(ta);
                out[(size_t)node * 40 + f] = ra;
            }
        }
    }
}

// ===========================================================================
// gather2 v4: out += mean(tmp[nbr]); tmp bf16 40/row = 80B = 10 x 8B units.
// Quarter-wave edges (lanes l<10 active per quarter), id prefetch as gather1.
// ===========================================================================
__global__ __launch_bounds__(256) void gather2_kernel(
    const ull* __restrict__ t64, const int* __restrict__ offs,
    const int* __restrict__ nbr, float* __restrict__ out)
{
    int lane = threadIdx.x & 63;
    int q    = lane >> 4;
    int l    = lane & 15;
    int cl   = (l < 10) ? l : 9;   // clamp: feats 4l..4l+3 valid for l<10
    int wv   = threadIdx.x >> 6;
    int node0 = blockIdx.x * 64;

    int oidx = node0 + wv + (lane >> 1) * 4 + (lane & 1);
    int ov = offs[min(oidx, N_NODES)];

    int beg_c = __shfl(ov, 0), end_c = __shfl(ov, 1);
    int safe0 = min(max(end_c - 1, beg_c), N_EDGES - 1);
    int id_pref = nbr[min(beg_c + lane, safe0)];

    for (int nn = 0; nn < 16; ++nn) {
        int beg = beg_c, end = end_c;
        int id  = id_pref;
        if (nn < 15) {
            beg_c = __shfl(ov, 2 * nn + 2);
            end_c = __shfl(ov, 2 * nn + 3);
            int safe = min(max(end_c - 1, beg_c), N_EDGES - 1);
            id_pref = nbr[min(beg_c + lane, safe)];
        }
        int node = node0 + nn * 4 + wv;
        if (node < N_NODES) {              // wave-uniform
            int deg = end - beg;
            float a0=0,a1=0,a2=0,a3=0, b0=0,b1=0,b2=0,b3=0;
            for (int c = 0; c < deg; c += 64) {
                if (c > 0) {
                    int safe = min(max(end - 1, beg), N_EDGES - 1);
                    id = nbr[min(beg + c + lane, safe)];
                }
                int cnt = min(deg - c, 64);
                for (int r = 0; r < cnt; r += 32) {
#pragma unroll
                    for (int i = 0; i < 8; ++i) {
                        int e   = r + i * 4 + q;
                        int ide = __shfl(id, min(e, cnt - 1));
                        ull w   = t64[(size_t)ide * 10 + cl];
                        bool val = (e < cnt);
                        unsigned int wlo = (unsigned int)w;
                        unsigned int whi = (unsigned int)(w >> 32);
                        float f0 = val ? bf16lo(wlo) : 0.f;
                        float f1 = val ? bf16hi(wlo) : 0.f;
                        float f2 = val ? bf16lo(whi) : 0.f;
                        float f3 = val ? bf16hi(whi) : 0.f;
                        if (i & 1) { b0 += f0; b1 += f1; b2 += f2; b3 += f3; }
                        else       { a0 += f0; a1 += f1; a2 += f2; a3 += f3; }
                    }
                }
            }
            a0 += b0; a1 += b1; a2 += b2; a3 += b3;
            a0 += __shfl_xor(a0, 16); a0 += __shfl_xor(a0, 32);
            a1 += __shfl_xor(a1, 16); a1 += __shfl_xor(a1, 32);
            a2 += __shfl_xor(a2, 16); a2 += __shfl_xor(a2, 32);
            a3 += __shfl_xor(a3, 16); a3 += __shfl_xor(a3, 32);
            if (lane < 10) {
                float inv = 1.0f / (float)max(deg, 1);
                float4 o = ((float4*)out)[(size_t)node * 10 + l];
                o.x += a0 * inv;
                o.y += a1 * inv;
                o.z += a2 * inv;
                o.w += a3 * inv;
                ((float4*)out)[(size_t)node * 10 + l] = o;
            }
        }
    }
}

extern "C" void kernel_launch(void* const* d_in, const int* in_sizes, int n_in,
                              void* d_out, int out_size, void* d_ws, size_t ws_size,
                              hipStream_t stream)
{
    const float* x     = (const float*)d_in[0];
    const int*   ei    = (const int*)d_in[1];
    const float* W1l   = (const float*)d_in[2];
    const float* W1r   = (const float*)d_in[3];
    const float* b1    = (const float*)d_in[4];
    const float* gamma = (const float*)d_in[5];
    const float* beta  = (const float*)d_in[6];
    const float* W2l   = (const float*)d_in[7];
    const float* W2r   = (const float*)d_in[8];
    const float* b2    = (const float*)d_in[9];
    float* out = (float*)d_out;

    const int* src = ei;
    const int* dst = ei + N_EDGES;

    // workspace layout (~54 MB; 58.8 MB proven available):
    float* ws    = (float*)d_ws;
    float* hv    = ws;                               // f32 [N*64]
    float* sums  = hv + (size_t)N_NODES * 64;        // 64
    float* sumsq = sums + 64;
    float* scale = sumsq + 64;
    float* shift = scale + 64;
    unsigned short* u = (unsigned short*)(shift + 64);   // bf16 [N*64] (8B-aligned)
    unsigned short* tmpb = u;                        // bf16 [N*40], reuses u
    int* deg    = (int*)(u + (size_t)N_NODES * 64);  // N
    int* offs   = deg + N_NODES;                     // N+1
    int* cursor = offs + N_NODES + 1;                // N
    int* bsum   = cursor + N_NODES;                  // 128
    int* nbr    = bsum + 128;                        // E

    dim3 blk(256);

    // ---- CSR build ----
    hipMemsetAsync(deg, 0, (size_t)N_NODES * sizeof(int), stream);
    hipMemsetAsync(sums, 0, 256 * sizeof(float), stream);
    histogram_kernel<<<(N_EDGES + 255) / 256, blk, 0, stream>>>(dst, deg);
    scan1_kernel<<<NB_SCAN, 1024, 0, stream>>>(deg, offs, bsum);
    scan2_kernel<<<1, 128, 0, stream>>>(bsum);
    scan3_kernel<<<NB_SCAN, 1024, 0, stream>>>(offs, bsum, cursor);
    fill_kernel<<<(N_EDGES + 255) / 256, blk, 0, stream>>>(src, dst, cursor, nbr);

    int dblocks = (N_NODES + 63) / 64;
    int gblocks = (N_NODES + 63) / 64;

    // ---- layer 1 ----
    dense1_lin_kernel<<<dblocks, blk, 0, stream>>>(x, W1l, W1r, b1, u, hv);
    gather1_bn_kernel<<<gblocks, blk, 0, stream>>>(
        (const ull*)u, offs, nbr, hv, sums, sumsq);
    bn_finalize_kernel<<<1, 64, 0, stream>>>(sums, sumsq, gamma, beta, scale, shift);

    // ---- layer 2 (BN+ReLU fused into dense2) ----
    dense2_bn_kernel<<<dblocks, blk, 0, stream>>>(
        hv, scale, shift, W2l, W2r, b2, tmpb, out);
    gather2_kernel<<<gblocks, blk, 0, stream>>>(
        (const ull*)tmpb, offs, nbr, out);
}

// Round 9
// 598.710 us; speedup vs baseline: 1.0642x; 1.0642x over previous
//
#include <hip/hip_runtime.h>

#define N_NODES 100000
#define N_EDGES 1600000
#define BN_EPS 1e-5f
#define NB_SCAN 98   // ceil(100000/1024)

// broadcast lane k's value (readlane). Wave-uniform control flow ONLY.
__device__ __forceinline__ float bcast(float v, int k) {
    return __uint_as_float(__builtin_amdgcn_readlane(__float_as_uint(v), k));
}
__device__ __forceinline__ float bf16lo(unsigned int w) {
    return __uint_as_float(w << 16);
}
__device__ __forceinline__ float bf16hi(unsigned int w) {
    return __uint_as_float(w & 0xFFFF0000u);
}
__device__ __forceinline__ unsigned short f2bf(float x) {   // round-nearest-even
    unsigned int u = __float_as_uint(x);
    return (unsigned short)((u + 0x7FFF + ((u >> 16) & 1)) >> 16);
}

// ===========================================================================
// CSR build: histogram -> 3-kernel exclusive scan -> single-pass fill
// (R7's segmented fill regressed; R8 restored single-pass. fill is write-
// amplification-bound: 1.6M scattered 4B stores -> ~106 MB HBM writes.)
// ===========================================================================
__global__ __launch_bounds__(256) void histogram_kernel(
    const int* __restrict__ dst, int* __restrict__ deg)
{
    int e = blockIdx.x * 256 + threadIdx.x;
    if (e < N_EDGES) atomicAdd(&deg[dst[e]], 1);
}

__global__ __launch_bounds__(1024) void scan1_kernel(
    const int* __restrict__ deg, int* __restrict__ offs, int* __restrict__ bsum)
{
    __shared__ int tmp[1024];
    int gid = blockIdx.x * 1024 + threadIdx.x;
    int v = (gid < N_NODES) ? deg[gid] : 0;
    tmp[threadIdx.x] = v;
    __syncthreads();
    for (int off = 1; off < 1024; off <<= 1) {
        int t = (threadIdx.x >= off) ? tmp[threadIdx.x - off] : 0;
        __syncthreads();
        tmp[threadIdx.x] += t;
        __syncthreads();
    }
    if (gid < N_NODES) offs[gid] = tmp[threadIdx.x] - v;
    if (threadIdx.x == 1023) bsum[blockIdx.x] = tmp[1023];
}

__global__ void scan2_kernel(int* __restrict__ bsum)
{
    __shared__ int tmp[128];
    int v = (threadIdx.x < NB_SCAN) ? bsum[threadIdx.x] : 0;
    tmp[threadIdx.x] = v;
    __syncthreads();
    for (int off = 1; off < 128; off <<= 1) {
        int t = (threadIdx.x >= off) ? tmp[threadIdx.x - off] : 0;
        __syncthreads();
        tmp[threadIdx.x] += t;
        __syncthreads();
    }
    if (threadIdx.x < NB_SCAN) bsum[threadIdx.x] = tmp[threadIdx.x] - v;
}

__global__ __launch_bounds__(1024) void scan3_kernel(
    int* __restrict__ offs, const int* __restrict__ bsum, int* __restrict__ cursor)
{
    int gid = blockIdx.x * 1024 + threadIdx.x;
    if (gid < N_NODES) {
        int v = offs[gid] + bsum[blockIdx.x];
        offs[gid] = v;
        cursor[gid] = v;
    }
    if (gid == 0) offs[N_NODES] = N_EDGES;
}

__global__ __launch_bounds__(256) void fill_kernel(
    const int* __restrict__ src, const int* __restrict__ dst,
    int* __restrict__ cursor, int* __restrict__ nbr)
{
    int e = blockIdx.x * 256 + threadIdx.x;
    if (e < N_EDGES) {
        int p = atomicAdd(&cursor[dst[e]], 1);
        nbr[p] = src[e];
    }
}

// ===========================================================================
// dense1_lin: u(bf16) = x @ W1l^T ; hv(f32) = x @ W1r^T + b1.
// ===========================================================================
__global__ __launch_bounds__(256) void dense1_lin_kernel(
    const float* __restrict__ x, const float* __restrict__ W1l,
    const float* __restrict__ W1r, const float* __restrict__ b1,
    unsigned short* __restrict__ u, float* __restrict__ hv)
{
    __shared__ float wlT[64 * 65];
    __shared__ float wrT[64 * 65];
    for (int idx = threadIdx.x; idx < 4096; idx += 256) {
        int f = idx >> 6, k = idx & 63;
        wlT[k * 65 + f] = W1l[idx];
        wrT[k * 65 + f] = W1r[idx];
    }
    __syncthreads();

    int f  = threadIdx.x & 63;
    int wv = threadIdx.x >> 6;
    float wl[64], wr[64];
#pragma unroll
    for (int k = 0; k < 64; ++k) {
        wl[k] = wlT[k * 65 + f];
        wr[k] = wrT[k * 65 + f];
    }
    float bias = b1[f];
    int node0 = blockIdx.x * 64;

    for (int nn = 0; nn < 16; ++nn) {
        int node = node0 + nn * 4 + wv;          // wave-uniform
        if (node < N_NODES) {
            float xv = x[(size_t)node * 64 + f];
            float ua = 0.f, va = bias;
#pragma unroll
            for (int k = 0; k < 64; ++k) {
                float xb = bcast(xv, k);
                ua += xb * wl[k];
                va += xb * wr[k];
            }
            u[(size_t)node * 64 + f]  = f2bf(ua);
            hv[(size_t)node * 64 + f] = va;
        }
    }
}

// ===========================================================================
// gather1_bn v3 (R7, proven 112 us): per 64-edge chunk ONE coalesced id
// load; gather rounds take ids via __shfl. Half-wave edge pairs, 16 nodes
// per wave, masked rounds, no serialized remainder.
// ===========================================================================
__global__ __launch_bounds__(256) void gather1_bn_kernel(
    const unsigned int* __restrict__ u32, const int* __restrict__ offs,
    const int* __restrict__ nbr, float* __restrict__ hv,
    float* __restrict__ sums, float* __restrict__ sumsq)
{
    int lane = threadIdx.x & 63;
    int m    = lane & 31;
    int half = lane >> 5;
    int wv   = threadIdx.x >> 6;
    int node0 = blockIdx.x * 64;
    float s1_0 = 0.f, s1_1 = 0.f, s2_0 = 0.f, s2_1 = 0.f;

    for (int nn = 0; nn < 16; ++nn) {
        int node = node0 + nn * 4 + wv;
        if (node < N_NODES) {                    // wave-uniform
            int beg = offs[node], end = offs[node + 1];
            int deg = end - beg;
            float p0=0,p1=0,p2=0,p3=0,q0=0,q1=0,q2=0,q3=0;
            for (int c = 0; c < deg; c += 64) {  // ~always 1 iteration
                int idx = beg + c + lane;
                int id  = nbr[(idx < end) ? idx : (end - 1)];  // coalesced
                int cnt = min(deg - c, 64);
                for (int r = 0; r < cnt; r += 16) {   // wave-uniform trips
#pragma unroll
                    for (int i = 0; i < 8; ++i) {
                        int e   = r + 2 * i + half;   // < 64 always
                        int ide = __shfl(id, e);      // id from registers
                        unsigned int w = u32[(size_t)ide * 32 + m];
                        bool val = (e < cnt);
                        float lo = val ? bf16lo(w) : 0.f;
                        float hi = val ? bf16hi(w) : 0.f;
                        if ((i & 3) == 0)      { p0 += lo; q0 += hi; }
                        else if ((i & 3) == 1) { p1 += lo; q1 += hi; }
                        else if ((i & 3) == 2) { p2 += lo; q2 += hi; }
                        else                   { p3 += lo; q3 += hi; }
                    }
                }
            }
            float P = (p0 + p1) + (p2 + p3);
            float Q = (q0 + q1) + (q2 + q3);
            P += __shfl_xor(P, 32);    // combine the two half-waves
            Q += __shfl_xor(Q, 32);
            if (half == 0) {
                float inv = 1.0f / (float)max(deg, 1);
                float2 v = ((const float2*)hv)[(size_t)node * 32 + m];
                float h0 = P * inv + v.x;
                float h1 = Q * inv + v.y;
                ((float2*)hv)[(size_t)node * 32 + m] = make_float2(h0, h1);
                s1_0 += h0; s1_1 += h1;
                s2_0 += h0 * h0; s2_1 += h1 * h1;
            }
        }
    }

    __shared__ float2 redA[256];
    __shared__ float2 redB[256];
    redA[threadIdx.x] = make_float2(s1_0, s1_1);
    redB[threadIdx.x] = make_float2(s2_0, s2_1);
    __syncthreads();
    if (threadIdx.x < 32) {
        int mm = threadIdx.x;
        float a0=0,a1=0,b0=0,b1=0;
        for (int w = 0; w < 4; ++w) {
            float2 A = redA[w * 64 + mm]; a0 += A.x; a1 += A.y;
            float2 B = redB[w * 64 + mm]; b0 += B.x; b1 += B.y;
        }
        atomicAdd(&sums[2 * mm], a0);  atomicAdd(&sums[2 * mm + 1], a1);
        atomicAdd(&sumsq[2 * mm], b0); atomicAdd(&sumsq[2 * mm + 1], b1);
    }
}

// ===========================================================================
// BN finalize
// ===========================================================================
__global__ void bn_finalize_kernel(
    const float* __restrict__ sums, const float* __restrict__ sumsq,
    const float* __restrict__ gamma, const float* __restrict__ beta,
    float* __restrict__ scale, float* __restrict__ shift)
{
    int f = threadIdx.x;
    if (f < 64) {
        float inv_n = 1.0f / (float)N_NODES;
        float mu  = sums[f] * inv_n;
        float var = sumsq[f] * inv_n - mu * mu;
        float rs  = rsqrtf(var + BN_EPS);
        float sc  = gamma[f] * rs;
        scale[f] = sc;
        shift[f] = beta[f] - mu * sc;
    }
}

// ===========================================================================
// dense2_bn: BN+ReLU fused; tmp(bf16, stride 20 dwords) = hn @ W2l^T;
// out = hn @ W2r^T + b2. Uniform readlane flow; stores predicated.
// ===========================================================================
__global__ __launch_bounds__(256) void dense2_bn_kernel(
    const float* __restrict__ h, const float* __restrict__ scale,
    const float* __restrict__ shift, const float* __restrict__ W2l,
    const float* __restrict__ W2r, const float* __restrict__ b2,
    unsigned short* __restrict__ tmp, float* __restrict__ out)
{
    __shared__ float wlT[64 * 65];
    __shared__ float wrT[64 * 65];
    for (int idx = threadIdx.x; idx < 2560; idx += 256) {
        int f = idx >> 6, k = idx & 63;      // f < 40
        wlT[k * 65 + f] = W2l[idx];
        wrT[k * 65 + f] = W2r[idx];
    }
    __syncthreads();

    int f  = threadIdx.x & 63;
    int wv = threadIdx.x >> 6;
    int fc = (f < 40) ? f : 39;
    float wl[64], wr[64];
#pragma unroll
    for (int k = 0; k < 64; ++k) {
        wl[k] = wlT[k * 65 + fc];
        wr[k] = wrT[k * 65 + fc];
    }
    float bias = b2[fc];
    float sc = scale[f], sh = shift[f];
    int node0 = blockIdx.x * 64;

    for (int nn = 0; nn < 16; ++nn) {
        int node = node0 + nn * 4 + wv;          // wave-uniform
        if (node < N_NODES) {
            float hvv = h[(size_t)node * 64 + f];
            float hn  = fmaxf(hvv * sc + sh, 0.f);   // BN + ReLU fused
            float ta = 0.f, ra = bias;
#pragma unroll
            for (int k = 0; k < 64; ++k) {
                float hb = bcast(hn, k);
                ta += hb * wl[k];
                ra += hb * wr[k];
            }
            if (f < 40) {
                tmp[(size_t)node * 40 + f] = f2bf(ta);
                out[(size_t)node * 40 + f] = ra;
            }
        }
    }
}

// ===========================================================================
// gather2 v3 (R7): out += mean(tmp[nbr]); tmp bf16 stride 20 dwords (80B).
// Same id-preload + shfl structure as gather1.
// ===========================================================================
__global__ __launch_bounds__(256) void gather2_kernel(
    const unsigned int* __restrict__ t32, const int* __restrict__ offs,
    const int* __restrict__ nbr, float* __restrict__ out)
{
    int lane = threadIdx.x & 63;
    int m    = lane & 31;
    int half = lane >> 5;
    bool act = (m < 20);
    int wv   = threadIdx.x >> 6;
    int node0 = blockIdx.x * 64;

    for (int nn = 0; nn < 16; ++nn) {
        int node = node0 + nn * 4 + wv;
        if (node < N_NODES) {                    // wave-uniform
            int beg = offs[node], end = offs[node + 1];
            int deg = end - beg;
            float p0=0,p1=0,p2=0,p3=0,q0=0,q1=0,q2=0,q3=0;
            for (int c = 0; c < deg; c += 64) {
                int idx = beg + c + lane;
                int id  = nbr[(idx < end) ? idx : (end - 1)];  // all lanes
                int cnt = min(deg - c, 64);
                for (int r = 0; r < cnt; r += 16) {
#pragma unroll
                    for (int i = 0; i < 8; ++i) {
                        int e   = r + 2 * i + half;
                        int ide = __shfl(id, e);     // all lanes execute
                        if (act) {
                            unsigned int w = t32[(size_t)ide * 20 + m];
                            bool val = (e < cnt);
                            float lo = val ? bf16lo(w) : 0.f;
                            float hi = val ? bf16hi(w) : 0.f;
                            if ((i & 3) == 0)      { p0 += lo; q0 += hi; }
                            else if ((i & 3) == 1) { p1 += lo; q1 += hi; }
                            else if ((i & 3) == 2) { p2 += lo; q2 += hi; }
                            else                   { p3 += lo; q3 += hi; }
                        }
                    }
                }
            }
            float P = (p0 + p1) + (p2 + p3);
            float Q = (q0 + q1) + (q2 + q3);
            P += __shfl_xor(P, 32);
            Q += __shfl_xor(Q, 32);
            if (half == 0 && act) {
                float inv = 1.0f / (float)max(deg, 1);
                float2 o = ((float2*)out)[(size_t)node * 20 + m];
                o.x += P * inv;
                o.y += Q * inv;
                ((float2*)out)[(size_t)node * 20 + m] = o;
            }
        }
    }
}

extern "C" void kernel_launch(void* const* d_in, const int* in_sizes, int n_in,
                              void* d_out, int out_size, void* d_ws, size_t ws_size,
                              hipStream_t stream)
{
    const float* x     = (const float*)d_in[0];
    const int*   ei    = (const int*)d_in[1];
    const float* W1l   = (const float*)d_in[2];
    const float* W1r   = (const float*)d_in[3];
    const float* b1    = (const float*)d_in[4];
    const float* gamma = (const float*)d_in[5];
    const float* beta  = (const float*)d_in[6];
    const float* W2l   = (const float*)d_in[7];
    const float* W2r   = (const float*)d_in[8];
    const float* b2    = (const float*)d_in[9];
    float* out = (float*)d_out;

    const int* src = ei;
    const int* dst = ei + N_EDGES;

    // workspace layout (~54 MB; 58.8 MB proven available):
    float* ws    = (float*)d_ws;
    float* hv    = ws;                               // f32 [N*64]
    float* sums  = hv + (size_t)N_NODES * 64;        // 64
    float* sumsq = sums + 64;
    float* scale = sumsq + 64;
    float* shift = scale + 64;
    unsigned short* u = (unsigned short*)(shift + 64);   // bf16 [N*64]
    unsigned short* tmpb = u;                        // bf16 [N*40], reuses u
    int* deg    = (int*)(u + (size_t)N_NODES * 64);  // N
    int* offs   = deg + N_NODES;                     // N+1
    int* cursor = offs + N_NODES + 1;                // N
    int* bsum   = cursor + N_NODES;                  // 128
    int* nbr    = bsum + 128;                        // E

    dim3 blk(256);

    // ---- CSR build ----
    hipMemsetAsync(deg, 0, (size_t)N_NODES * sizeof(int), stream);
    hipMemsetAsync(sums, 0, 256 * sizeof(float), stream);
    histogram_kernel<<<(N_EDGES + 255) / 256, blk, 0, stream>>>(dst, deg);
    scan1_kernel<<<NB_SCAN, 1024, 0, stream>>>(deg, offs, bsum);
    scan2_kernel<<<1, 128, 0, stream>>>(bsum);
    scan3_kernel<<<NB_SCAN, 1024, 0, stream>>>(offs, bsum, cursor);
    fill_kernel<<<(N_EDGES + 255) / 256, blk, 0, stream>>>(src, dst, cursor, nbr);

    int dblocks = (N_NODES + 63) / 64;
    int gblocks = (N_NODES + 63) / 64;

    // ---- layer 1 ----
    dense1_lin_kernel<<<dblocks, blk, 0, stream>>>(x, W1l, W1r, b1, u, hv);
    gather1_bn_kernel<<<gblocks, blk, 0, stream>>>(
        (const unsigned int*)u, offs, nbr, hv, sums, sumsq);
    bn_finalize_kernel<<<1, 64, 0, stream>>>(sums, sumsq, gamma, beta, scale, shift);

    // ---- layer 2 (BN+ReLU fused into dense2) ----
    dense2_bn_kernel<<<dblocks, blk, 0, stream>>>(
        hv, scale, shift, W2l, W2r, b2, tmpb, out);
    gather2_kernel<<<gblocks, blk, 0, stream>>>(
        (const unsigned int*)tmpb, offs, nbr, out);
}

// Round 10
// 552.920 us; speedup vs baseline: 1.1523x; 1.0828x over previous
//
#include <hip/hip_runtime.h>

#define N_NODES 100000
#define N_EDGES 1600000
#define BN_EPS 1e-5f
#define NB_SCAN 98       // ceil(100000/1024)
#define PART_SZ 12500    // N_NODES / 8 XCD partitions
#define FILL_CHUNKS 1024
#define CHUNK_SZ 1563    // ceil(N_EDGES / FILL_CHUNKS)

// broadcast lane k's value (readlane). Wave-uniform control flow ONLY.
__device__ __forceinline__ float bcast(float v, int k) {
    return __uint_as_float(__builtin_amdgcn_readlane(__float_as_uint(v), k));
}
__device__ __forceinline__ float bf16lo(unsigned int w) {
    return __uint_as_float(w << 16);
}
__device__ __forceinline__ float bf16hi(unsigned int w) {
    return __uint_as_float(w & 0xFFFF0000u);
}
__device__ __forceinline__ unsigned short f2bf(float x) {   // round-nearest-even
    unsigned int u = __float_as_uint(x);
    return (unsigned short)((u + 0x7FFF + ((u >> 16) & 1)) >> 16);
}

// ===========================================================================
// CSR build, XCD-partitioned: grid = FILL_CHUNKS x 8. Block b scans edge
// chunk b>>3, keeps edges whose dst lies in partition (b&7)*PART_SZ.. —
// with round-robin block->XCD dispatch each XCD's L2 exclusively owns its
// 1/8 slice of deg/cursor/nbr, so scattered stores/atomics merge in L2
// instead of ping-ponging across non-coherent XCD L2s (R9: 106 MB HBM
// writes for a 6.4 MB array). dst is re-read 8x (streaming, L3-cheap).
// ===========================================================================
__global__ __launch_bounds__(256) void histogram_xcd_kernel(
    const int* __restrict__ dst, int* __restrict__ deg)
{
    int part  = blockIdx.x & 7;
    int lo = part * PART_SZ, hi = lo + PART_SZ;
    int base  = (blockIdx.x >> 3) * CHUNK_SZ;
    int endE  = min(base + CHUNK_SZ, N_EDGES);
    for (int e = base + threadIdx.x; e < endE; e += 256) {
        int d = dst[e];
        if (d >= lo && d < hi) atomicAdd(&deg[d], 1);
    }
}

__global__ __launch_bounds__(256) void fill_xcd_kernel(
    const int* __restrict__ src, const int* __restrict__ dst,
    int* __restrict__ cursor, int* __restrict__ nbr)
{
    int part  = blockIdx.x & 7;
    int lo = part * PART_SZ, hi = lo + PART_SZ;
    int base  = (blockIdx.x >> 3) * CHUNK_SZ;
    int endE  = min(base + CHUNK_SZ, N_EDGES);
    for (int e = base + threadIdx.x; e < endE; e += 256) {
        int d = dst[e];
        if (d >= lo && d < hi) {
            int p = atomicAdd(&cursor[d], 1);
            nbr[p] = src[e];
        }
    }
}

__global__ __launch_bounds__(1024) void scan1_kernel(
    const int* __restrict__ deg, int* __restrict__ offs, int* __restrict__ bsum)
{
    __shared__ int tmp[1024];
    int gid = blockIdx.x * 1024 + threadIdx.x;
    int v = (gid < N_NODES) ? deg[gid] : 0;
    tmp[threadIdx.x] = v;
    __syncthreads();
    for (int off = 1; off < 1024; off <<= 1) {
        int t = (threadIdx.x >= off) ? tmp[threadIdx.x - off] : 0;
        __syncthreads();
        tmp[threadIdx.x] += t;
        __syncthreads();
    }
    if (gid < N_NODES) offs[gid] = tmp[threadIdx.x] - v;
    if (threadIdx.x == 1023) bsum[blockIdx.x] = tmp[1023];
}

__global__ void scan2_kernel(int* __restrict__ bsum)
{
    __shared__ int tmp[128];
    int v = (threadIdx.x < NB_SCAN) ? bsum[threadIdx.x] : 0;
    tmp[threadIdx.x] = v;
    __syncthreads();
    for (int off = 1; off < 128; off <<= 1) {
        int t = (threadIdx.x >= off) ? tmp[threadIdx.x - off] : 0;
        __syncthreads();
        tmp[threadIdx.x] += t;
        __syncthreads();
    }
    if (threadIdx.x < NB_SCAN) bsum[threadIdx.x] = tmp[threadIdx.x] - v;
}

__global__ __launch_bounds__(1024) void scan3_kernel(
    int* __restrict__ offs, const int* __restrict__ bsum, int* __restrict__ cursor)
{
    int gid = blockIdx.x * 1024 + threadIdx.x;
    if (gid < N_NODES) {
        int v = offs[gid] + bsum[blockIdx.x];
        offs[gid] = v;
        cursor[gid] = v;
    }
    if (gid == 0) offs[N_NODES] = N_EDGES;
}

// ===========================================================================
// dense1_lin: u(bf16) = x @ W1l^T ; hv(f32) = x @ W1r^T + b1.
// ===========================================================================
__global__ __launch_bounds__(256) void dense1_lin_kernel(
    const float* __restrict__ x, const float* __restrict__ W1l,
    const float* __restrict__ W1r, const float* __restrict__ b1,
    unsigned short* __restrict__ u, float* __restrict__ hv)
{
    __shared__ float wlT[64 * 65];
    __shared__ float wrT[64 * 65];
    for (int idx = threadIdx.x; idx < 4096; idx += 256) {
        int f = idx >> 6, k = idx & 63;
        wlT[k * 65 + f] = W1l[idx];
        wrT[k * 65 + f] = W1r[idx];
    }
    __syncthreads();

    int f  = threadIdx.x & 63;
    int wv = threadIdx.x >> 6;
    float wl[64], wr[64];
#pragma unroll
    for (int k = 0; k < 64; ++k) {
        wl[k] = wlT[k * 65 + f];
        wr[k] = wrT[k * 65 + f];
    }
    float bias = b1[f];
    int node0 = blockIdx.x * 64;

    for (int nn = 0; nn < 16; ++nn) {
        int node = node0 + nn * 4 + wv;          // wave-uniform
        if (node < N_NODES) {
            float xv = x[(size_t)node * 64 + f];
            float ua = 0.f, va = bias;
#pragma unroll
            for (int k = 0; k < 64; ++k) {
                float xb = bcast(xv, k);
                ua += xb * wl[k];
                va += xb * wr[k];
            }
            u[(size_t)node * 64 + f]  = f2bf(ua);
            hv[(size_t)node * 64 + f] = va;
        }
    }
}

// ===========================================================================
// gather1_bn v3 (proven 112 us): per 64-edge chunk ONE coalesced id load;
// gather rounds take ids via __shfl. Half-wave edge pairs, 16 nodes/wave.
// ===========================================================================
__global__ __launch_bounds__(256) void gather1_bn_kernel(
    const unsigned int* __restrict__ u32, const int* __restrict__ offs,
    const int* __restrict__ nbr, float* __restrict__ hv,
    float* __restrict__ sums, float* __restrict__ sumsq)
{
    int lane = threadIdx.x & 63;
    int m    = lane & 31;
    int half = lane >> 5;
    int wv   = threadIdx.x >> 6;
    int node0 = blockIdx.x * 64;
    float s1_0 = 0.f, s1_1 = 0.f, s2_0 = 0.f, s2_1 = 0.f;

    for (int nn = 0; nn < 16; ++nn) {
        int node = node0 + nn * 4 + wv;
        if (node < N_NODES) {                    // wave-uniform
            int beg = offs[node], end = offs[node + 1];
            int deg = end - beg;
            float p0=0,p1=0,p2=0,p3=0,q0=0,q1=0,q2=0,q3=0;
            for (int c = 0; c < deg; c += 64) {  // ~always 1 iteration
                int idx = beg + c + lane;
                int id  = nbr[(idx < end) ? idx : (end - 1)];  // coalesced
                int cnt = min(deg - c, 64);
                for (int r = 0; r < cnt; r += 16) {   // wave-uniform trips
#pragma unroll
                    for (int i = 0; i < 8; ++i) {
                        int e   = r + 2 * i + half;   // < 64 always
                        int ide = __shfl(id, e);      // id from registers
                        unsigned int w = u32[(size_t)ide * 32 + m];
                        bool val = (e < cnt);
                        float lo = val ? bf16lo(w) : 0.f;
                        float hi = val ? bf16hi(w) : 0.f;
                        if ((i & 3) == 0)      { p0 += lo; q0 += hi; }
                        else if ((i & 3) == 1) { p1 += lo; q1 += hi; }
                        else if ((i & 3) == 2) { p2 += lo; q2 += hi; }
                        else                   { p3 += lo; q3 += hi; }
                    }
                }
            }
            float P = (p0 + p1) + (p2 + p3);
            float Q = (q0 + q1) + (q2 + q3);
            P += __shfl_xor(P, 32);    // combine the two half-waves
            Q += __shfl_xor(Q, 32);
            if (half == 0) {
                float inv = 1.0f / (float)max(deg, 1);
                float2 v = ((const float2*)hv)[(size_t)node * 32 + m];
                float h0 = P * inv + v.x;
                float h1 = Q * inv + v.y;
                ((float2*)hv)[(size_t)node * 32 + m] = make_float2(h0, h1);
                s1_0 += h0; s1_1 += h1;
                s2_0 += h0 * h0; s2_1 += h1 * h1;
            }
        }
    }

    __shared__ float2 redA[256];
    __shared__ float2 redB[256];
    redA[threadIdx.x] = make_float2(s1_0, s1_1);
    redB[threadIdx.x] = make_float2(s2_0, s2_1);
    __syncthreads();
    if (threadIdx.x < 32) {
        int mm = threadIdx.x;
        float a0=0,a1=0,b0=0,b1=0;
        for (int w = 0; w < 4; ++w) {
            float2 A = redA[w * 64 + mm]; a0 += A.x; a1 += A.y;
            float2 B = redB[w * 64 + mm]; b0 += B.x; b1 += B.y;
        }
        atomicAdd(&sums[2 * mm], a0);  atomicAdd(&sums[2 * mm + 1], a1);
        atomicAdd(&sumsq[2 * mm], b0); atomicAdd(&sumsq[2 * mm + 1], b1);
    }
}

// ===========================================================================
// BN finalize
// ===========================================================================
__global__ void bn_finalize_kernel(
    const float* __restrict__ sums, const float* __restrict__ sumsq,
    const float* __restrict__ gamma, const float* __restrict__ beta,
    float* __restrict__ scale, float* __restrict__ shift)
{
    int f = threadIdx.x;
    if (f < 64) {
        float inv_n = 1.0f / (float)N_NODES;
        float mu  = sums[f] * inv_n;
        float var = sumsq[f] * inv_n - mu * mu;
        float rs  = rsqrtf(var + BN_EPS);
        float sc  = gamma[f] * rs;
        scale[f] = sc;
        shift[f] = beta[f] - mu * sc;
    }
}

// ===========================================================================
// dense2_bn: BN+ReLU fused; tmp(bf16, stride 20 dwords) = hn @ W2l^T;
// out = hn @ W2r^T + b2. Uniform readlane flow; stores predicated.
// ===========================================================================
__global__ __launch_bounds__(256) void dense2_bn_kernel(
    const float* __restrict__ h, const float* __restrict__ scale,
    const float* __restrict__ shift, const float* __restrict__ W2l,
    const float* __restrict__ W2r, const float* __restrict__ b2,
    unsigned short* __restrict__ tmp, float* __restrict__ out)
{
    __shared__ float wlT[64 * 65];
    __shared__ float wrT[64 * 65];
    for (int idx = threadIdx.x; idx < 2560; idx += 256) {
        int f = idx >> 6, k = idx & 63;      // f < 40
        wlT[k * 65 + f] = W2l[idx];
        wrT[k * 65 + f] = W2r[idx];
    }
    __syncthreads();

    int f  = threadIdx.x & 63;
    int wv = threadIdx.x >> 6;
    int fc = (f < 40) ? f : 39;
    float wl[64], wr[64];
#pragma unroll
    for (int k = 0; k < 64; ++k) {
        wl[k] = wlT[k * 65 + fc];
        wr[k] = wrT[k * 65 + fc];
    }
    float bias = b2[fc];
    float sc = scale[f], sh = shift[f];
    int node0 = blockIdx.x * 64;

    for (int nn = 0; nn < 16; ++nn) {
        int node = node0 + nn * 4 + wv;          // wave-uniform
        if (node < N_NODES) {
            float hvv = h[(size_t)node * 64 + f];
            float hn  = fmaxf(hvv * sc + sh, 0.f);   // BN + ReLU fused
            float ta = 0.f, ra = bias;
#pragma unroll
            for (int k = 0; k < 64; ++k) {
                float hb = bcast(hn, k);
                ta += hb * wl[k];
                ra += hb * wr[k];
            }
            if (f < 40) {
                tmp[(size_t)node * 40 + f] = f2bf(ta);
                out[(size_t)node * 40 + f] = ra;
            }
        }
    }
}

// ===========================================================================
// gather2 v3: out += mean(tmp[nbr]); tmp bf16 stride 20 dwords (80B rows).
// ===========================================================================
__global__ __launch_bounds__(256) void gather2_kernel(
    const unsigned int* __restrict__ t32, const int* __restrict__ offs,
    const int* __restrict__ nbr, float* __restrict__ out)
{
    int lane = threadIdx.x & 63;
    int m    = lane & 31;
    int half = lane >> 5;
    bool act = (m < 20);
    int wv   = threadIdx.x >> 6;
    int node0 = blockIdx.x * 64;

    for (int nn = 0; nn < 16; ++nn) {
        int node = node0 + nn * 4 + wv;
        if (node < N_NODES) {                    // wave-uniform
            int beg = offs[node], end = offs[node + 1];
            int deg = end - beg;
            float p0=0,p1=0,p2=0,p3=0,q0=0,q1=0,q2=0,q3=0;
            for (int c = 0; c < deg; c += 64) {
                int idx = beg + c + lane;
                int id  = nbr[(idx < end) ? idx : (end - 1)];  // all lanes
                int cnt = min(deg - c, 64);
                for (int r = 0; r < cnt; r += 16) {
#pragma unroll
                    for (int i = 0; i < 8; ++i) {
                        int e   = r + 2 * i + half;
                        int ide = __shfl(id, e);     // all lanes execute
                        if (act) {
                            unsigned int w = t32[(size_t)ide * 20 + m];
                            bool val = (e < cnt);
                            float lo = val ? bf16lo(w) : 0.f;
                            float hi = val ? bf16hi(w) : 0.f;
                            if ((i & 3) == 0)      { p0 += lo; q0 += hi; }
                            else if ((i & 3) == 1) { p1 += lo; q1 += hi; }
                            else if ((i & 3) == 2) { p2 += lo; q2 += hi; }
                            else                   { p3 += lo; q3 += hi; }
                        }
                    }
                }
            }
            float P = (p0 + p1) + (p2 + p3);
            float Q = (q0 + q1) + (q2 + q3);
            P += __shfl_xor(P, 32);
            Q += __shfl_xor(Q, 32);
            if (half == 0 && act) {
                float inv = 1.0f / (float)max(deg, 1);
                float2 o = ((float2*)out)[(size_t)node * 20 + m];
                o.x += P * inv;
                o.y += Q * inv;
                ((float2*)out)[(size_t)node * 20 + m] = o;
            }
        }
    }
}

extern "C" void kernel_launch(void* const* d_in, const int* in_sizes, int n_in,
                              void* d_out, int out_size, void* d_ws, size_t ws_size,
                              hipStream_t stream)
{
    const float* x     = (const float*)d_in[0];
    const int*   ei    = (const int*)d_in[1];
    const float* W1l   = (const float*)d_in[2];
    const float* W1r   = (const float*)d_in[3];
    const float* b1    = (const float*)d_in[4];
    const float* gamma = (const float*)d_in[5];
    const float* beta  = (const float*)d_in[6];
    const float* W2l   = (const float*)d_in[7];
    const float* W2r   = (const float*)d_in[8];
    const float* b2    = (const float*)d_in[9];
    float* out = (float*)d_out;

    const int* src = ei;
    const int* dst = ei + N_EDGES;

    // workspace layout (~54 MB; 58.8 MB proven available):
    float* ws    = (float*)d_ws;
    float* hv    = ws;                               // f32 [N*64]
    float* sums  = hv + (size_t)N_NODES * 64;        // 64
    float* sumsq = sums + 64;
    float* scale = sumsq + 64;
    float* shift = scale + 64;
    unsigned short* u = (unsigned short*)(shift + 64);   // bf16 [N*64]
    unsigned short* tmpb = u;                        // bf16 [N*40], reuses u
    int* deg    = (int*)(u + (size_t)N_NODES * 64);  // N
    int* offs   = deg + N_NODES;                     // N+1
    int* cursor = offs + N_NODES + 1;                // N
    int* bsum   = cursor + N_NODES;                  // 128
    int* nbr    = bsum + 128;                        // E

    dim3 blk(256);

    // ---- CSR build (XCD-partitioned histogram + fill) ----
    hipMemsetAsync(deg, 0, (size_t)N_NODES * sizeof(int), stream);
    hipMemsetAsync(sums, 0, 256 * sizeof(float), stream);
    histogram_xcd_kernel<<<FILL_CHUNKS * 8, blk, 0, stream>>>(dst, deg);
    scan1_kernel<<<NB_SCAN, 1024, 0, stream>>>(deg, offs, bsum);
    scan2_kernel<<<1, 128, 0, stream>>>(bsum);
    scan3_kernel<<<NB_SCAN, 1024, 0, stream>>>(offs, bsum, cursor);
    fill_xcd_kernel<<<FILL_CHUNKS * 8, blk, 0, stream>>>(src, dst, cursor, nbr);

    int dblocks = (N_NODES + 63) / 64;
    int gblocks = (N_NODES + 63) / 64;

    // ---- layer 1 ----
    dense1_lin_kernel<<<dblocks, blk, 0, stream>>>(x, W1l, W1r, b1, u, hv);
    gather1_bn_kernel<<<gblocks, blk, 0, stream>>>(
        (const unsigned int*)u, offs, nbr, hv, sums, sumsq);
    bn_finalize_kernel<<<1, 64, 0, stream>>>(sums, sumsq, gamma, beta, scale, shift);

    // ---- layer 2 (BN+ReLU fused into dense2) ----
    dense2_bn_kernel<<<dblocks, blk, 0, stream>>>(
        hv, scale, shift, W2l, W2r, b2, tmpb, out);
    gather2_kernel<<<gblocks, blk, 0, stream>>>(
        (const unsigned int*)tmpb, offs, nbr, out);
}